// Round 7
// baseline (235.715 us; speedup 1.0000x reference)
//
#include <hip/hip_runtime.h>
#include <math.h>

#define NB 32
#define NT 4096
#define ND 512
#define NA 64
#define NCHUNK 16          // t-chunks for context partials
#define TCHUNK (NT / NCHUNK)

// ---------------------------------------------------------------- scores ----
// scores[b,t] = w2 . tanh(W1 @ x[b,t] + b1)
// ALL of W1 (128 KB) in LDS for the whole kernel; ONE barrier.
// R6 post-mortem: LDS return-bus bound (8.4 GB LDS reads @ 69 TB/s = 122 us
// floor at R=2 rows/thread; broadcast doesn't save return cycles).
// LDS-bytes/FMA = 4/R -> R=4 balances LDS (1 B/FMA) against the 157 TF
// FMA-issue pipe (0.88 B/FMA). Thread tile = 4 rows x 8 a-cols; wv is
// consumed immediately per j (live set ~75 regs, under the 128 cap of
// 4 waves/SIMD). 1024 thr/block, 512 rows/block -> 256 blocks = 1/CU.
#define SB 1024            // threads per block
#define RPB 512            // rows per block -> 256 blocks
#define ND4 (ND / 4)       // 128 float4 per a-row

__global__ __launch_bounds__(SB, 4) void k_scores(
    const float* __restrict__ x, const float* __restrict__ W1,
    const float* __restrict__ b1, const float* __restrict__ w2,
    float* __restrict__ scores)
{
    __shared__ float4 wl[NA * ND4];            // 128 KB

    const int tid = threadIdx.x;
    const int ag  = tid & 7;                   // a-group: cols ag*8 .. +7
    const int rg  = tid >> 3;                  // 128 row-groups x 4 rows
    const size_t row0 = (size_t)blockIdx.x * RPB + (size_t)rg * 4;

    const float4* __restrict__ x4 = reinterpret_cast<const float4*>(x);
    const float4* __restrict__ W4 = reinterpret_cast<const float4*>(W1);

    // stage ALL of W1 into LDS (swizzled), coalesced: 8 float4 per thread
#pragma unroll
    for (int r = 0; r < 8; ++r) {
        int i  = r * SB + tid;
        int a  = i >> 7;                       // / ND4
        int dq = i & (ND4 - 1);
        wl[a * ND4 + (dq ^ (a >> 3))] = W4[i];
    }
    __syncthreads();                           // the only barrier

    const float4* __restrict__ xp0 = x4 + (row0 + 0) * ND4;
    const float4* __restrict__ xp1 = x4 + (row0 + 1) * ND4;
    const float4* __restrict__ xp2 = x4 + (row0 + 2) * ND4;
    const float4* __restrict__ xp3 = x4 + (row0 + 3) * ND4;
    const float4* __restrict__ wbase = wl + (size_t)ag * 8 * ND4;

    float acc[4][8];
#pragma unroll
    for (int r = 0; r < 4; ++r)
#pragma unroll
        for (int j = 0; j < 8; ++j) acc[r][j] = 0.f;

#pragma unroll 2
    for (int dq = 0; dq < ND4; ++dq) {
        float4 x0 = xp0[dq];
        float4 x1 = xp1[dq];
        float4 x2 = xp2[dq];
        float4 x3 = xp3[dq];
        const int dsw = dq ^ ag;
#pragma unroll
        for (int j = 0; j < 8; ++j) {
            float4 wv = wbase[j * ND4 + dsw];  // consumed immediately
            acc[0][j] = fmaf(x0.x, wv.x, acc[0][j]);
            acc[0][j] = fmaf(x0.y, wv.y, acc[0][j]);
            acc[0][j] = fmaf(x0.z, wv.z, acc[0][j]);
            acc[0][j] = fmaf(x0.w, wv.w, acc[0][j]);
            acc[1][j] = fmaf(x1.x, wv.x, acc[1][j]);
            acc[1][j] = fmaf(x1.y, wv.y, acc[1][j]);
            acc[1][j] = fmaf(x1.z, wv.z, acc[1][j]);
            acc[1][j] = fmaf(x1.w, wv.w, acc[1][j]);
            acc[2][j] = fmaf(x2.x, wv.x, acc[2][j]);
            acc[2][j] = fmaf(x2.y, wv.y, acc[2][j]);
            acc[2][j] = fmaf(x2.z, wv.z, acc[2][j]);
            acc[2][j] = fmaf(x2.w, wv.w, acc[2][j]);
            acc[3][j] = fmaf(x3.x, wv.x, acc[3][j]);
            acc[3][j] = fmaf(x3.y, wv.y, acc[3][j]);
            acc[3][j] = fmaf(x3.z, wv.z, acc[3][j]);
            acc[3][j] = fmaf(x3.w, wv.w, acc[3][j]);
        }
    }

    // epilogue: p_r = sum_j w2[ag*8+j] * tanh(acc[r][j] + b1[ag*8+j])
    float b1v[8], w2v[8];
#pragma unroll
    for (int j = 0; j < 8; ++j) {
        b1v[j] = b1[ag * 8 + j];
        w2v[j] = w2[ag * 8 + j];
    }
    float p[4];
#pragma unroll
    for (int r = 0; r < 4; ++r) {
        float s = 0.f;
#pragma unroll
        for (int j = 0; j < 8; ++j)
            s += w2v[j] * tanhf(acc[r][j] + b1v[j]);
        p[r] = s;
    }
#pragma unroll
    for (int off = 1; off < 8; off <<= 1)
#pragma unroll
        for (int r = 0; r < 4; ++r) p[r] += __shfl_xor(p[r], off);

    if (ag == 0) {
#pragma unroll
        for (int r = 0; r < 4; ++r) scores[row0 + r] = p[r];
    }
}

// --------------------------------------------------------------- softmax ----
__global__ __launch_bounds__(256) void k_softmax(
    const float* __restrict__ scores, const int* __restrict__ mask,
    float* __restrict__ weights)
{
    __shared__ float e_lds[NT];    // 16 KB
    __shared__ float red[4];

    int b = blockIdx.x;
    const float* srow = scores + (size_t)b * NT;
    const int*   mrow = mask   + (size_t)b * NT;

    float m = -INFINITY;
    for (int i = 0; i < NT / 256; ++i) {
        int t = i * 256 + threadIdx.x;
        float s = srow[t];
        bool valid = (mrow[t] != 0);
        e_lds[t] = valid ? s : -INFINITY;
        if (valid) m = fmaxf(m, s);
    }
#pragma unroll
    for (int off = 32; off; off >>= 1) m = fmaxf(m, __shfl_xor(m, off));
    if ((threadIdx.x & 63) == 0) red[threadIdx.x >> 6] = m;
    __syncthreads();
    m = fmaxf(fmaxf(red[0], red[1]), fmaxf(red[2], red[3]));
    __syncthreads();

    float sum = 0.f;
    for (int i = 0; i < NT / 256; ++i) {
        int t = i * 256 + threadIdx.x;
        float e = expf(e_lds[t] - m);
        e_lds[t] = e;
        sum += e;
    }
#pragma unroll
    for (int off = 32; off; off >>= 1) sum += __shfl_xor(sum, off);
    if ((threadIdx.x & 63) == 0) red[threadIdx.x >> 6] = sum;
    __syncthreads();
    float total = (red[0] + red[1]) + (red[2] + red[3]);
    float inv = 1.f / total;

    for (int i = 0; i < NT / 256; ++i) {
        int t = i * 256 + threadIdx.x;
        weights[(size_t)b * NT + t] = e_lds[t] * inv;
    }
}

// ------------------------------------------------------- context partials ---
__global__ __launch_bounds__(512) void k_ctx_partial(
    const float* __restrict__ x, const float* __restrict__ weights,
    float* __restrict__ partials)
{
    int b = blockIdx.x >> 4;
    int c = blockIdx.x & (NCHUNK - 1);
    int d = threadIdx.x;

    const float* xp = x + ((size_t)b * NT + (size_t)c * TCHUNK) * ND + d;
    const float* wp = weights + (size_t)b * NT + (size_t)c * TCHUNK;

    float acc = 0.f;
#pragma unroll 4
    for (int t = 0; t < TCHUNK; ++t)
        acc = fmaf(wp[t], xp[(size_t)t * ND], acc);

    partials[(size_t)blockIdx.x * ND + d] = acc;
}

// -------------------------------------------------------- context reduce ----
__global__ __launch_bounds__(256) void k_ctx_reduce(
    const float* __restrict__ partials, float* __restrict__ ctx)
{
    int i = blockIdx.x * 256 + threadIdx.x;   // b*ND + d
    int b = i >> 9;
    int d = i & (ND - 1);
    float s = 0.f;
#pragma unroll
    for (int c = 0; c < NCHUNK; ++c)
        s += partials[((size_t)(b * NCHUNK + c)) * ND + d];
    ctx[i] = s;
}

// ------------------------------------------------------------------ launch --
extern "C" void kernel_launch(void* const* d_in, const int* in_sizes, int n_in,
                              void* d_out, int out_size, void* d_ws, size_t ws_size,
                              hipStream_t stream)
{
    const float* x    = (const float*)d_in[0];
    const int*   mask = (const int*)d_in[1];
    const float* W1   = (const float*)d_in[2];
    const float* b1   = (const float*)d_in[3];
    const float* w2   = (const float*)d_in[4];

    float* ctx     = (float*)d_out;                  // B*D
    float* weights = (float*)d_out + NB * ND;        // B*T
    float* scores   = (float*)d_ws;                  // B*T
    float* partials = (float*)d_ws + NB * NT;        // B*NCHUNK*D

    k_scores<<<(NB * NT) / RPB, SB, 0, stream>>>(x, W1, b1, w2, scores);
    k_softmax<<<NB, 256, 0, stream>>>(scores, mask, weights);
    k_ctx_partial<<<NB * NCHUNK, 512, 0, stream>>>(x, weights, partials);
    k_ctx_reduce<<<NB * ND / 256, 256, 0, stream>>>(partials, ctx);
}

// Round 8
// 184.960 us; speedup vs baseline: 1.2744x; 1.2744x over previous
//
#include <hip/hip_runtime.h>
#include <math.h>

#define NB 32
#define NT 4096
#define ND 512
#define NA 64
#define NCHUNK 16          // t-chunks for context partials
#define TCHUNK (NT / NCHUNK)

// ---------------------------------------------------------------- scores ----
// scores[b,t] = w2 . tanh(W1 @ x[b,t] + b1)
// ALL of W1 (128 KB) in LDS; ONE barrier. Thread tile = 4 rows x 8 a-cols
// (LDS bytes/FMA = 1, balancing the 78 TB/s LDS return bus against the
// 157 TF FMA pipe at 4 waves/SIMD). R7 lesson: #pragma unroll 2 held 2
// iterations of xv (32 regs) -> compiler spilled at its chosen 64-VGPR
// budget (WRITE_SIZE 130 MB). Fix: unroll 1 + 2 base pointers with
// immediate row offsets -> live set ~58 regs, fits 64, no spills.
#define SB 1024            // threads per block
#define RPB 512            // rows per block -> 256 blocks = 1/CU
#define ND4 (ND / 4)       // 128 float4 per a-row

__global__ __launch_bounds__(SB, 4) void k_scores(
    const float* __restrict__ x, const float* __restrict__ W1,
    const float* __restrict__ b1, const float* __restrict__ w2,
    float* __restrict__ scores)
{
    __shared__ float4 wl[NA * ND4];            // 128 KB

    const int tid = threadIdx.x;
    const int ag  = tid & 7;                   // a-group: cols ag*8 .. +7
    const int rg  = tid >> 3;                  // 128 row-groups x 4 rows
    const size_t row0 = (size_t)blockIdx.x * RPB + (size_t)rg * 4;

    const float4* __restrict__ x4 = reinterpret_cast<const float4*>(x);
    const float4* __restrict__ W4 = reinterpret_cast<const float4*>(W1);

    // stage ALL of W1 into LDS (swizzled), coalesced: 8 float4 per thread
#pragma unroll
    for (int r = 0; r < 8; ++r) {
        int i  = r * SB + tid;
        int a  = i >> 7;                       // / ND4
        int dq = i & (ND4 - 1);
        wl[a * ND4 + (dq ^ (a >> 3))] = W4[i];
    }
    __syncthreads();                           // the only barrier

    // two base pointers; second row of each pair at +ND4 (2 KB imm offset)
    const float4* __restrict__ xpA = x4 + (row0 + 0) * ND4;
    const float4* __restrict__ xpB = x4 + (row0 + 2) * ND4;
    const float4* __restrict__ wbase = wl + (size_t)ag * 8 * ND4;

    float acc[4][8];
#pragma unroll
    for (int r = 0; r < 4; ++r)
#pragma unroll
        for (int j = 0; j < 8; ++j) acc[r][j] = 0.f;

#pragma unroll 1
    for (int dq = 0; dq < ND4; ++dq) {
        float4 x0 = xpA[dq];
        float4 x1 = xpA[dq + ND4];
        float4 x2 = xpB[dq];
        float4 x3 = xpB[dq + ND4];
        const int dsw = dq ^ ag;
#pragma unroll
        for (int j = 0; j < 8; ++j) {
            float4 wv = wbase[j * ND4 + dsw];  // consumed immediately
            acc[0][j] = fmaf(x0.x, wv.x, acc[0][j]);
            acc[0][j] = fmaf(x0.y, wv.y, acc[0][j]);
            acc[0][j] = fmaf(x0.z, wv.z, acc[0][j]);
            acc[0][j] = fmaf(x0.w, wv.w, acc[0][j]);
            acc[1][j] = fmaf(x1.x, wv.x, acc[1][j]);
            acc[1][j] = fmaf(x1.y, wv.y, acc[1][j]);
            acc[1][j] = fmaf(x1.z, wv.z, acc[1][j]);
            acc[1][j] = fmaf(x1.w, wv.w, acc[1][j]);
            acc[2][j] = fmaf(x2.x, wv.x, acc[2][j]);
            acc[2][j] = fmaf(x2.y, wv.y, acc[2][j]);
            acc[2][j] = fmaf(x2.z, wv.z, acc[2][j]);
            acc[2][j] = fmaf(x2.w, wv.w, acc[2][j]);
            acc[3][j] = fmaf(x3.x, wv.x, acc[3][j]);
            acc[3][j] = fmaf(x3.y, wv.y, acc[3][j]);
            acc[3][j] = fmaf(x3.z, wv.z, acc[3][j]);
            acc[3][j] = fmaf(x3.w, wv.w, acc[3][j]);
        }
    }

    // epilogue: p_r = sum_j w2[ag*8+j] * tanh(acc[r][j] + b1[ag*8+j])
    float b1v[8], w2v[8];
#pragma unroll
    for (int j = 0; j < 8; ++j) {
        b1v[j] = b1[ag * 8 + j];
        w2v[j] = w2[ag * 8 + j];
    }
    float p[4];
#pragma unroll
    for (int r = 0; r < 4; ++r) {
        float s = 0.f;
#pragma unroll
        for (int j = 0; j < 8; ++j)
            s += w2v[j] * tanhf(acc[r][j] + b1v[j]);
        p[r] = s;
    }
#pragma unroll
    for (int off = 1; off < 8; off <<= 1)
#pragma unroll
        for (int r = 0; r < 4; ++r) p[r] += __shfl_xor(p[r], off);

    if (ag == 0) {
#pragma unroll
        for (int r = 0; r < 4; ++r) scores[row0 + r] = p[r];
    }
}

// --------------------------------------------------------------- softmax ----
__global__ __launch_bounds__(256) void k_softmax(
    const float* __restrict__ scores, const int* __restrict__ mask,
    float* __restrict__ weights)
{
    __shared__ float e_lds[NT];    // 16 KB
    __shared__ float red[4];

    int b = blockIdx.x;
    const float* srow = scores + (size_t)b * NT;
    const int*   mrow = mask   + (size_t)b * NT;

    float m = -INFINITY;
    for (int i = 0; i < NT / 256; ++i) {
        int t = i * 256 + threadIdx.x;
        float s = srow[t];
        bool valid = (mrow[t] != 0);
        e_lds[t] = valid ? s : -INFINITY;
        if (valid) m = fmaxf(m, s);
    }
#pragma unroll
    for (int off = 32; off; off >>= 1) m = fmaxf(m, __shfl_xor(m, off));
    if ((threadIdx.x & 63) == 0) red[threadIdx.x >> 6] = m;
    __syncthreads();
    m = fmaxf(fmaxf(red[0], red[1]), fmaxf(red[2], red[3]));
    __syncthreads();

    float sum = 0.f;
    for (int i = 0; i < NT / 256; ++i) {
        int t = i * 256 + threadIdx.x;
        float e = expf(e_lds[t] - m);
        e_lds[t] = e;
        sum += e;
    }
#pragma unroll
    for (int off = 32; off; off >>= 1) sum += __shfl_xor(sum, off);
    if ((threadIdx.x & 63) == 0) red[threadIdx.x >> 6] = sum;
    __syncthreads();
    float total = (red[0] + red[1]) + (red[2] + red[3]);
    float inv = 1.f / total;

    for (int i = 0; i < NT / 256; ++i) {
        int t = i * 256 + threadIdx.x;
        weights[(size_t)b * NT + t] = e_lds[t] * inv;
    }
}

// ------------------------------------------------------- context partials ---
__global__ __launch_bounds__(512) void k_ctx_partial(
    const float* __restrict__ x, const float* __restrict__ weights,
    float* __restrict__ partials)
{
    int b = blockIdx.x >> 4;
    int c = blockIdx.x & (NCHUNK - 1);
    int d = threadIdx.x;

    const float* xp = x + ((size_t)b * NT + (size_t)c * TCHUNK) * ND + d;
    const float* wp = weights + (size_t)b * NT + (size_t)c * TCHUNK;

    float acc = 0.f;
#pragma unroll 4
    for (int t = 0; t < TCHUNK; ++t)
        acc = fmaf(wp[t], xp[(size_t)t * ND], acc);

    partials[(size_t)blockIdx.x * ND + d] = acc;
}

// -------------------------------------------------------- context reduce ----
__global__ __launch_bounds__(256) void k_ctx_reduce(
    const float* __restrict__ partials, float* __restrict__ ctx)
{
    int i = blockIdx.x * 256 + threadIdx.x;   // b*ND + d
    int b = i >> 9;
    int d = i & (ND - 1);
    float s = 0.f;
#pragma unroll
    for (int c = 0; c < NCHUNK; ++c)
        s += partials[((size_t)(b * NCHUNK + c)) * ND + d];
    ctx[i] = s;
}

// ------------------------------------------------------------------ launch --
extern "C" void kernel_launch(void* const* d_in, const int* in_sizes, int n_in,
                              void* d_out, int out_size, void* d_ws, size_t ws_size,
                              hipStream_t stream)
{
    const float* x    = (const float*)d_in[0];
    const int*   mask = (const int*)d_in[1];
    const float* W1   = (const float*)d_in[2];
    const float* b1   = (const float*)d_in[3];
    const float* w2   = (const float*)d_in[4];

    float* ctx     = (float*)d_out;                  // B*D
    float* weights = (float*)d_out + NB * ND;        // B*T
    float* scores   = (float*)d_ws;                  // B*T
    float* partials = (float*)d_ws + NB * NT;        // B*NCHUNK*D

    k_scores<<<(NB * NT) / RPB, SB, 0, stream>>>(x, W1, b1, w2, scores);
    k_softmax<<<NB, 256, 0, stream>>>(scores, mask, weights);
    k_ctx_partial<<<NB * NCHUNK, 512, 0, stream>>>(x, weights, partials);
    k_ctx_reduce<<<NB * ND / 256, 256, 0, stream>>>(partials, ctx);
}

// Round 9
// 122.905 us; speedup vs baseline: 1.9179x; 1.5049x over previous
//
#include <hip/hip_runtime.h>
#include <math.h>

#define NB 32
#define NT 4096
#define ND 512
#define NA 64
#define NCHUNK 16          // t-chunks for context partials
#define TCHUNK (NT / NCHUNK)

typedef __attribute__((ext_vector_type(8))) short short8;   // 8 bf16 (4 VGPR)
typedef __attribute__((ext_vector_type(4))) float f32x4;    // MFMA acc

// ---- split-bf16 helpers: f = hi(trunc bf16) + lo(RNE bf16 of residual) ----
__device__ __forceinline__ uint rne16(float r) {
    uint v = __float_as_uint(r);
    v += 0x7fffu + ((v >> 16) & 1u);
    return v;                       // bf16 bits in [31:16]
}
__device__ __forceinline__ void split2(float f0, float f1, uint& hw, uint& lw) {
    uint u0 = __float_as_uint(f0), u1 = __float_as_uint(f1);
    hw = (u0 >> 16) | (u1 & 0xffff0000u);
    float r0 = f0 - __uint_as_float(u0 & 0xffff0000u);
    float r1 = f1 - __uint_as_float(u1 & 0xffff0000u);
    lw = (rne16(r0) >> 16) | (rne16(r1) & 0xffff0000u);
}
__device__ __forceinline__ void split8(float4 a, float4 b, short8& hi, short8& lo) {
    union U { short8 s; uint u[4]; } H, L;
    split2(a.x, a.y, H.u[0], L.u[0]);
    split2(a.z, a.w, H.u[1], L.u[1]);
    split2(b.x, b.y, H.u[2], L.u[2]);
    split2(b.z, b.w, H.u[3], L.u[3]);
    hi = H.s; lo = L.s;
}

// ------------------------------------------------------------------ prep ----
// Pack W1 into MFMA B-fragments (hi/lo bf16). Fragment (ks,nt,lane):
// elem e = W1[a = nt*16 + (l&15)][k = ks*32 + (l>>4)*8 + e].
// fidx = (ks*4 + nt)*64 + l == global thread id (4096 threads).
__global__ __launch_bounds__(256) void k_prep(
    const float* __restrict__ W1, short8* __restrict__ whi, short8* __restrict__ wlo)
{
    int t = blockIdx.x * 256 + threadIdx.x;       // 0..4095
    int l  = t & 63;
    int nt = (t >> 6) & 3;
    int ks = t >> 8;
    int a  = nt * 16 + (l & 15);
    int kb = ks * 32 + (l >> 4) * 8;
    const float* p = W1 + a * ND + kb;
    float4 u = *(const float4*)p;
    float4 v = *(const float4*)(p + 4);
    short8 hi, lo;
    split8(u, v, hi, lo);
    whi[t] = hi;
    wlo[t] = lo;
}

// ---------------------------------------------------------------- scores ----
// scores[b,t] = w2 . tanh(W1 @ x[b,t] + b1) -- on the MATRIX cores.
// Split-bf16 GEMM: x=xhi+xlo, W=whi+wlo; acc += xhi*whi + xhi*wlo + xlo*whi
// (drop lo*lo; ~1e-5 rel err << 2.75e-3 threshold). 16x16x32 bf16 MFMA.
// Wave = 64 rows x 64 a-cols = 4 mt-tiles x 4 nt-tiles; block = 4 waves
// = 256 rows -> 512 blocks. No LDS; W fragments pre-packed (L2-resident).
// A-frag: lane l elem e = x[row0+mt*16+(l&15)][ks*32+(l>>4)*8+e] -> the
// two float4 x-loads per (mt,ks) are fully line-dense per wave (16 rows x
// 64 B, every byte consumed). C-layout (m89): row=(l>>4)*4+r, col=l&15.
__global__ __launch_bounds__(256, 4) void k_scores(
    const float* __restrict__ x,
    const short8* __restrict__ whi, const short8* __restrict__ wlo,
    const float* __restrict__ b1, const float* __restrict__ w2,
    float* __restrict__ scores)
{
    const int tid = threadIdx.x;
    const int l   = tid & 63;
    const int wv  = tid >> 6;
    const int lr  = l & 15;
    const int lq  = l >> 4;
    const size_t row0 = (size_t)blockIdx.x * 256 + (size_t)wv * 64;

    const float* xb = x + (row0 + lr) * ND + lq * 8;

    f32x4 acc[4][4];
#pragma unroll
    for (int mt = 0; mt < 4; ++mt)
#pragma unroll
        for (int nt = 0; nt < 4; ++nt) acc[mt][nt] = (f32x4)0.f;

    for (int ks = 0; ks < 16; ++ks) {
        short8 ahi[4], alo[4];
#pragma unroll
        for (int mt = 0; mt < 4; ++mt) {
            const float* p = xb + mt * 16 * ND + ks * 32;
            float4 u = *(const float4*)p;
            float4 v = *(const float4*)(p + 4);
            split8(u, v, ahi[mt], alo[mt]);
        }
#pragma unroll
        for (int nt = 0; nt < 4; ++nt) {
            short8 bh = whi[(ks * 4 + nt) * 64 + l];
            short8 bl = wlo[(ks * 4 + nt) * 64 + l];
#pragma unroll
            for (int mt = 0; mt < 4; ++mt) {
                acc[mt][nt] = __builtin_amdgcn_mfma_f32_16x16x32_bf16(ahi[mt], bh, acc[mt][nt], 0, 0, 0);
                acc[mt][nt] = __builtin_amdgcn_mfma_f32_16x16x32_bf16(ahi[mt], bl, acc[mt][nt], 0, 0, 0);
                acc[mt][nt] = __builtin_amdgcn_mfma_f32_16x16x32_bf16(alo[mt], bh, acc[mt][nt], 0, 0, 0);
            }
        }
    }

    // epilogue: lane holds h[row=(lq*4+r)+mt*16][a=nt*16+lr] for r,nt,mt
    float w2v[4], b1v[4];
#pragma unroll
    for (int nt = 0; nt < 4; ++nt) {
        w2v[nt] = w2[nt * 16 + lr];
        b1v[nt] = b1[nt * 16 + lr];
    }
#pragma unroll
    for (int mt = 0; mt < 4; ++mt) {
#pragma unroll
        for (int r = 0; r < 4; ++r) {
            float s = 0.f;
#pragma unroll
            for (int nt = 0; nt < 4; ++nt)
                s += w2v[nt] * tanhf(acc[mt][nt][r] + b1v[nt]);
            // reduce over the 16 lanes (lr) sharing this row
            s += __shfl_xor(s, 1);
            s += __shfl_xor(s, 2);
            s += __shfl_xor(s, 4);
            s += __shfl_xor(s, 8);
            if (lr == 0)
                scores[row0 + mt * 16 + lq * 4 + r] = s;
        }
    }
}

// --------------------------------------------------------------- softmax ----
__global__ __launch_bounds__(256) void k_softmax(
    const float* __restrict__ scores, const int* __restrict__ mask,
    float* __restrict__ weights)
{
    __shared__ float e_lds[NT];    // 16 KB
    __shared__ float red[4];

    int b = blockIdx.x;
    const float* srow = scores + (size_t)b * NT;
    const int*   mrow = mask   + (size_t)b * NT;

    float m = -INFINITY;
    for (int i = 0; i < NT / 256; ++i) {
        int t = i * 256 + threadIdx.x;
        float s = srow[t];
        bool valid = (mrow[t] != 0);
        e_lds[t] = valid ? s : -INFINITY;
        if (valid) m = fmaxf(m, s);
    }
#pragma unroll
    for (int off = 32; off; off >>= 1) m = fmaxf(m, __shfl_xor(m, off));
    if ((threadIdx.x & 63) == 0) red[threadIdx.x >> 6] = m;
    __syncthreads();
    m = fmaxf(fmaxf(red[0], red[1]), fmaxf(red[2], red[3]));
    __syncthreads();

    float sum = 0.f;
    for (int i = 0; i < NT / 256; ++i) {
        int t = i * 256 + threadIdx.x;
        float e = expf(e_lds[t] - m);
        e_lds[t] = e;
        sum += e;
    }
#pragma unroll
    for (int off = 32; off; off >>= 1) sum += __shfl_xor(sum, off);
    if ((threadIdx.x & 63) == 0) red[threadIdx.x >> 6] = sum;
    __syncthreads();
    float total = (red[0] + red[1]) + (red[2] + red[3]);
    float inv = 1.f / total;

    for (int i = 0; i < NT / 256; ++i) {
        int t = i * 256 + threadIdx.x;
        weights[(size_t)b * NT + t] = e_lds[t] * inv;
    }
}

// ------------------------------------------------------- context partials ---
__global__ __launch_bounds__(512) void k_ctx_partial(
    const float* __restrict__ x, const float* __restrict__ weights,
    float* __restrict__ partials)
{
    int b = blockIdx.x >> 4;
    int c = blockIdx.x & (NCHUNK - 1);
    int d = threadIdx.x;

    const float* xp = x + ((size_t)b * NT + (size_t)c * TCHUNK) * ND + d;
    const float* wp = weights + (size_t)b * NT + (size_t)c * TCHUNK;

    float acc = 0.f;
#pragma unroll 4
    for (int t = 0; t < TCHUNK; ++t)
        acc = fmaf(wp[t], xp[(size_t)t * ND], acc);

    partials[(size_t)blockIdx.x * ND + d] = acc;
}

// -------------------------------------------------------- context reduce ----
__global__ __launch_bounds__(256) void k_ctx_reduce(
    const float* __restrict__ partials, float* __restrict__ ctx)
{
    int i = blockIdx.x * 256 + threadIdx.x;   // b*ND + d
    int b = i >> 9;
    int d = i & (ND - 1);
    float s = 0.f;
#pragma unroll
    for (int c = 0; c < NCHUNK; ++c)
        s += partials[((size_t)(b * NCHUNK + c)) * ND + d];
    ctx[i] = s;
}

// ------------------------------------------------------------------ launch --
extern "C" void kernel_launch(void* const* d_in, const int* in_sizes, int n_in,
                              void* d_out, int out_size, void* d_ws, size_t ws_size,
                              hipStream_t stream)
{
    const float* x    = (const float*)d_in[0];
    const int*   mask = (const int*)d_in[1];
    const float* W1   = (const float*)d_in[2];
    const float* b1   = (const float*)d_in[3];
    const float* w2   = (const float*)d_in[4];

    float* ctx     = (float*)d_out;                  // B*D
    float* weights = (float*)d_out + NB * ND;        // B*T
    float* scores   = (float*)d_ws;                  // B*T floats
    float* partials = (float*)d_ws + NB * NT;        // B*NCHUNK*D floats
    short8* whi = (short8*)((float*)d_ws + NB * NT + NB * NCHUNK * ND); // 64 KB
    short8* wlo = whi + 16 * 4 * 64;                                    // 64 KB

    k_prep<<<16, 256, 0, stream>>>(W1, whi, wlo);
    k_scores<<<(NB * NT) / 256, 256, 0, stream>>>(x, whi, wlo, b1, w2, scores);
    k_softmax<<<NB, 256, 0, stream>>>(scores, mask, weights);
    k_ctx_partial<<<NB * NCHUNK, 512, 0, stream>>>(x, weights, partials);
    k_ctx_reduce<<<NB * ND / 256, 256, 0, stream>>>(partials, ctx);
}

// Round 10
// 115.180 us; speedup vs baseline: 2.0465x; 1.0671x over previous
//
#include <hip/hip_runtime.h>
#include <math.h>

#define NB 32
#define NT 4096
#define ND 512
#define NA 64
#define TC 32                  // rows per staged chunk
#define CPB 8                  // chunks per block (256 rows/block)
#define BPB (NT / (TC * CPB))  // 16 blocks per batch row -> grid 512
#define ND4 (ND / 4)           // 128 float4 units per x-row

typedef __attribute__((ext_vector_type(8))) short short8;   // 8 bf16
typedef __attribute__((ext_vector_type(4))) float f32x4;    // MFMA acc

// ---- split-bf16 helpers: f = hi(trunc bf16) + lo(RNE bf16 of residual) ----
__device__ __forceinline__ uint rne16(float r) {
    uint v = __float_as_uint(r);
    v += 0x7fffu + ((v >> 16) & 1u);
    return v;
}
__device__ __forceinline__ void split2(float f0, float f1, uint& hw, uint& lw) {
    uint u0 = __float_as_uint(f0), u1 = __float_as_uint(f1);
    hw = (u0 >> 16) | (u1 & 0xffff0000u);
    float r0 = f0 - __uint_as_float(u0 & 0xffff0000u);
    float r1 = f1 - __uint_as_float(u1 & 0xffff0000u);
    lw = (rne16(r0) >> 16) | (rne16(r1) & 0xffff0000u);
}
__device__ __forceinline__ void split8(float4 a, float4 b, short8& hi, short8& lo) {
    union U { short8 s; uint u[4]; } H, L;
    split2(a.x, a.y, H.u[0], L.u[0]);
    split2(a.z, a.w, H.u[1], L.u[1]);
    split2(b.x, b.y, H.u[2], L.u[2]);
    split2(b.z, b.w, H.u[3], L.u[3]);
    hi = H.s; lo = L.s;
}

// ------------------------------------------------------------------ prep ----
// Pack W1 into MFMA B-fragments (hi/lo bf16), fidx == global thread id.
__global__ __launch_bounds__(256) void k_prep(
    const float* __restrict__ W1, short8* __restrict__ whi, short8* __restrict__ wlo)
{
    int t = blockIdx.x * 256 + threadIdx.x;       // 0..4095
    int l  = t & 63;
    int nt = (t >> 6) & 3;
    int ks = t >> 8;
    int a  = nt * 16 + (l & 15);
    int kb = ks * 32 + (l >> 4) * 8;
    const float* p = W1 + a * ND + kb;
    float4 u = *(const float4*)p;
    float4 v = *(const float4*)(p + 4);
    short8 hi, lo;
    split8(u, v, hi, lo);
    whi[t] = hi;
    wlo[t] = lo;
}

// ----------------------------------------------------------------- fused ----
// Per block: 256 t-rows of one batch row, processed as 8 chunks of 32 rows.
// Per chunk: stage x-chunk (64 KB) to LDS (unit (t,c16) at c16^(t&7));
// waves 0-1 MFMA scores (split-bf16, as R9); online-softmax update; all
// threads accumulate ctx_run (thread = d-pair) from the SAME LDS copy.
// x is read from HBM exactly once.
__global__ __launch_bounds__(256) void k_fused(
    const float* __restrict__ x, const int* __restrict__ mask,
    const short8* __restrict__ whi, const short8* __restrict__ wlo,
    const float* __restrict__ b1, const float* __restrict__ w2,
    float* __restrict__ scores, float* __restrict__ pctx, float* __restrict__ pml)
{
    __shared__ float4 xl[TC * ND4];    // 64 KB
    __shared__ float sc[TC];
    __shared__ float ev[TC];

    const int tid = threadIdx.x;
    const int wv  = tid >> 6;
    const int l   = tid & 63;
    const int lr  = l & 15;
    const int lq  = l >> 4;
    const int b   = blockIdx.x >> 4;          // / BPB
    const int blk = blockIdx.x & (BPB - 1);
    const size_t t0 = (size_t)b * NT + (size_t)blk * (TC * CPB);

    const float4* __restrict__ x4 = reinterpret_cast<const float4*>(x);

    float w2v[4], b1v[4];
#pragma unroll
    for (int nt = 0; nt < 4; ++nt) {
        w2v[nt] = w2[nt * 16 + lr];
        b1v[nt] = b1[nt * 16 + lr];
    }

    float m_run = -INFINITY, l_run = 0.f;
    float cx = 0.f, cy = 0.f;                 // ctx for d0 = 2*tid, d0+1
    const int u  = tid >> 1;                  // phase-B unit index
    const int hb = (tid & 1) * 2;             // float offset within unit

    for (int c = 0; c < CPB; ++c) {
        const size_t row0 = t0 + (size_t)c * TC;

        // ---- stage chunk: 4096 units / 256 thr = 16 each, batched 8
        const float4* __restrict__ src = x4 + row0 * ND4;
#pragma unroll
        for (int g = 0; g < 2; ++g) {
            float4 tmp[8];
#pragma unroll
            for (int k2 = 0; k2 < 8; ++k2)
                tmp[k2] = src[(g * 8 + k2) * 256 + tid];
#pragma unroll
            for (int k2 = 0; k2 < 8; ++k2) {
                int i   = (g * 8 + k2) * 256 + tid;
                int t   = i >> 7;
                int c16 = i & (ND4 - 1);
                xl[t * ND4 + (c16 ^ (t & 7))] = tmp[k2];
            }
        }
        __syncthreads();                       // xl ready

        // ---- phase A: waves 0,1 -> scores for rows wv*16 .. +15
        if (wv < 2) {
            const int r   = wv * 16 + lr;
            const int rsw = r & 7;
            f32x4 acc[4];
#pragma unroll
            for (int nt = 0; nt < 4; ++nt) acc[nt] = (f32x4)0.f;

            for (int ks = 0; ks < 16; ++ks) {
                float4 ua = xl[r * ND4 + ((ks * 8 + lq * 2)     ^ rsw)];
                float4 ub = xl[r * ND4 + ((ks * 8 + lq * 2 + 1) ^ rsw)];
                short8 ahi, alo;
                split8(ua, ub, ahi, alo);
#pragma unroll
                for (int nt = 0; nt < 4; ++nt) {
                    short8 bh = whi[(ks * 4 + nt) * 64 + l];
                    short8 bl = wlo[(ks * 4 + nt) * 64 + l];
                    acc[nt] = __builtin_amdgcn_mfma_f32_16x16x32_bf16(ahi, bh, acc[nt], 0, 0, 0);
                    acc[nt] = __builtin_amdgcn_mfma_f32_16x16x32_bf16(ahi, bl, acc[nt], 0, 0, 0);
                    acc[nt] = __builtin_amdgcn_mfma_f32_16x16x32_bf16(alo, bh, acc[nt], 0, 0, 0);
                }
            }
            // epilogue: C row = lq*4 + rg, col = lr
#pragma unroll
            for (int rg = 0; rg < 4; ++rg) {
                float s = 0.f;
#pragma unroll
                for (int nt = 0; nt < 4; ++nt)
                    s += w2v[nt] * tanhf(acc[nt][rg] + b1v[nt]);
                s += __shfl_xor(s, 1);
                s += __shfl_xor(s, 2);
                s += __shfl_xor(s, 4);
                s += __shfl_xor(s, 8);
                if (lr == 0) {
                    int ridx = wv * 16 + lq * 4 + rg;
                    bool valid = (mask[row0 + ridx] != 0);
                    float sm = valid ? s : -INFINITY;
                    sc[ridx] = sm;
                    scores[row0 + ridx] = sm;
                }
            }
        }
        __syncthreads();                       // sc ready

        // ---- online-softmax update (uniform; LDS broadcast reads)
        float m_c = -INFINITY;
        for (int t = 0; t < TC; ++t) m_c = fmaxf(m_c, sc[t]);
        float m_new = fmaxf(m_run, m_c);
        float m_eff = (m_new == -INFINITY) ? 0.f : m_new;
        float scale = expf(m_run - m_eff);     // m_run=-inf -> 0
        if (tid < TC) ev[tid] = expf(sc[tid] - m_eff);
        __syncthreads();                       // ev ready

        float l_c = 0.f;
        for (int t = 0; t < TC; ++t) l_c += ev[t];

        // ---- phase B: ctx accumulate (thread = d-pair)
        cx *= scale; cy *= scale;
        for (int t = 0; t < TC; ++t) {
            float e = ev[t];
            const float* pu = (const float*)&xl[t * ND4 + (u ^ (t & 7))];
            cx = fmaf(e, pu[hb],     cx);
            cy = fmaf(e, pu[hb + 1], cy);
        }
        l_run = l_run * scale + l_c;
        m_run = m_new;
        __syncthreads();                       // WAR before next stage
    }

    const int d0 = 2 * tid;
    pctx[(size_t)blockIdx.x * ND + d0]     = cx;
    pctx[(size_t)blockIdx.x * ND + d0 + 1] = cy;
    if (tid == 0) {
        pml[blockIdx.x * 2]     = m_run;
        pml[blockIdx.x * 2 + 1] = l_run;
    }
}

// ----------------------------------------------------------------- merge ----
__global__ __launch_bounds__(256) void k_merge(
    const float* __restrict__ pctx, const float* __restrict__ pml,
    float* __restrict__ ctx, float* __restrict__ mbden)
{
    int b = blockIdx.x, tid = threadIdx.x;
    float m_b = -INFINITY;
    for (int i = 0; i < BPB; ++i) m_b = fmaxf(m_b, pml[(b * BPB + i) * 2]);
    float denom = 0.f;
    for (int i = 0; i < BPB; ++i) {
        float mi = pml[(b * BPB + i) * 2];
        float li = pml[(b * BPB + i) * 2 + 1];
        denom += li * expf(mi - m_b);          // mi=-inf -> 0
    }
    float inv = 1.f / denom;
    int d0 = 2 * tid;
    float a0 = 0.f, a1 = 0.f;
    for (int i = 0; i < BPB; ++i) {
        float s = expf(pml[(b * BPB + i) * 2] - m_b);
        a0 = fmaf(pctx[(size_t)(b * BPB + i) * ND + d0],     s, a0);
        a1 = fmaf(pctx[(size_t)(b * BPB + i) * ND + d0 + 1], s, a1);
    }
    ctx[(size_t)b * ND + d0]     = a0 * inv;
    ctx[(size_t)b * ND + d0 + 1] = a1 * inv;
    if (tid == 0) {
        mbden[b * 2]     = m_b;
        mbden[b * 2 + 1] = denom;
    }
}

// --------------------------------------------------------------- weights ----
__global__ __launch_bounds__(256) void k_weights(
    const float* __restrict__ scores, const float* __restrict__ mbden,
    float* __restrict__ weights)
{
    int i = blockIdx.x * 256 + threadIdx.x;   // over B*T
    int b = i >> 12;                          // / NT
    float m  = mbden[b * 2];
    float dn = mbden[b * 2 + 1];
    weights[i] = expf(scores[i] - m) / dn;    // s=-inf -> exactly 0
}

// ------------------------------------------------------------------ launch --
extern "C" void kernel_launch(void* const* d_in, const int* in_sizes, int n_in,
                              void* d_out, int out_size, void* d_ws, size_t ws_size,
                              hipStream_t stream)
{
    const float* x    = (const float*)d_in[0];
    const int*   mask = (const int*)d_in[1];
    const float* W1   = (const float*)d_in[2];
    const float* b1   = (const float*)d_in[3];
    const float* w2   = (const float*)d_in[4];

    float* ctx     = (float*)d_out;                  // B*D
    float* weights = (float*)d_out + NB * ND;        // B*T

    float* ws      = (float*)d_ws;
    float* scores  = ws;                              // B*T          (131072)
    float* pctx    = ws + NB * NT;                    // 512*ND       (262144)
    float* pml     = pctx + NB * BPB * ND;            // 512*2        (1024)
    float* mbden   = pml + NB * BPB * 2;              // 32*2         (64)
    short8* whi    = (short8*)(mbden + NB * 2);       // 64 KB
    short8* wlo    = whi + 16 * 4 * 64;               // 64 KB

    k_prep<<<16, 256, 0, stream>>>(W1, whi, wlo);
    k_fused<<<NB * BPB, 256, 0, stream>>>(x, mask, whi, wlo, b1, w2,
                                          scores, pctx, pml);
    k_merge<<<NB, 256, 0, stream>>>(pctx, pml, ctx, mbden);
    k_weights<<<NB * NT / 256, 256, 0, stream>>>(scores, mbden, weights);
}